// Round 6
// baseline (731.276 us; speedup 1.0000x reference)
//
#include <hip/hip_runtime.h>

// MoEUT time-series decoder, round 6.
// - attn_split: barrier-free flash attention. 32 Q-rows/block, each wave owns
//   a private 256-key chunk (8x32-key tiles, wave-private LDS, K-frags direct
//   from global), merge partial (m,l,O) across waves at the end.
// - mfma_gemm: double-buffered LDS, ONE barrier per K-iter (prefetch gets the
//   ds_read+MFMA window of head start before the barrier drain).

#define LNUM 3
#define D 1024
#define H 16
#define HD 64
#define E 8
#define EH 256
#define B 2
#define S 1024
#define DIN 32
#define NOUT 8
#define EPS 1e-5f
#define TOK (B * S)

typedef __bf16 bf16x8 __attribute__((ext_vector_type(8)));
typedef float fx4 __attribute__((ext_vector_type(4)));

// ---------------- reductions ----------------
__device__ inline float block_reduce_sum256(float v, float* scratch) {
  int lane = threadIdx.x & 63, wv = threadIdx.x >> 6;
#pragma unroll
  for (int off = 32; off; off >>= 1) v += __shfl_down(v, off);
  __syncthreads();
  if (lane == 0) scratch[wv] = v;
  __syncthreads();
  return scratch[0] + scratch[1] + scratch[2] + scratch[3];
}

// ---------------- LayerNorm -> bf16 ----------------
__global__ __launch_bounds__(256) void ln_bf_kernel(
    const float* __restrict__ in, const float* __restrict__ g,
    const float* __restrict__ bta, __bf16* __restrict__ outb) {
  int token = blockIdx.x;
  int tid = threadIdx.x;
  const float* p = in + (size_t)token * D;
  __shared__ float scratch[4];
  float x[4];
  float s = 0.f, sq = 0.f;
#pragma unroll
  for (int i = 0; i < 4; i++) {
    x[i] = p[tid + i * 256];
    s += x[i];
    sq += x[i] * x[i];
  }
  s = block_reduce_sum256(s, scratch);
  sq = block_reduce_sum256(sq, scratch);
  float mean = s * (1.f / D);
  float inv = rsqrtf(sq * (1.f / D) - mean * mean + EPS);
  __bf16* obp = outb + (size_t)token * D;
#pragma unroll
  for (int i = 0; i < 4; i++) {
    int d = tid + i * 256;
    obp[d] = (__bf16)((x[i] - mean) * inv * g[d] + bta[d]);
  }
}

// ---------------- LayerNorm + sigmoid gate top-2 (fused) ----------------
__global__ __launch_bounds__(256) void ln_gate_kernel(
    const float* __restrict__ in, const float* __restrict__ g,
    const float* __restrict__ bta, const float* __restrict__ selw,
    __bf16* __restrict__ outb, float* __restrict__ gm) {
  int token = blockIdx.x;
  int tid = threadIdx.x;
  const float* p = in + (size_t)token * D;
  __shared__ float scratch[4];
  float x[4];
  float s = 0.f, sq = 0.f;
#pragma unroll
  for (int i = 0; i < 4; i++) {
    x[i] = p[tid + i * 256];
    s += x[i];
    sq += x[i] * x[i];
  }
  s = block_reduce_sum256(s, scratch);
  sq = block_reduce_sum256(sq, scratch);
  float mean = s * (1.f / D);
  float inv = rsqrtf(sq * (1.f / D) - mean * mean + EPS);
  __bf16* obp = outb + (size_t)token * D;
  float ge[E];
#pragma unroll
  for (int e = 0; e < E; e++) ge[e] = 0.f;
#pragma unroll
  for (int i = 0; i < 4; i++) {
    int d = tid + i * 256;
    float y = (x[i] - mean) * inv * g[d] + bta[d];
    obp[d] = (__bf16)y;
#pragma unroll
    for (int e = 0; e < E; e++) ge[e] += y * selw[d * E + e];
  }
  __shared__ float red[4][E];
  int lane = tid & 63, wv = tid >> 6;
#pragma unroll
  for (int e = 0; e < E; e++) {
    float vv = ge[e];
#pragma unroll
    for (int off = 32; off; off >>= 1) vv += __shfl_down(vv, off);
    if (lane == 0) red[wv][e] = vv;
  }
  __syncthreads();
  if (tid == 0) {
    float gg[E];
    for (int e = 0; e < E; e++) {
      float sv = red[0][e] + red[1][e] + red[2][e] + red[3][e];
      gg[e] = 1.f / (1.f + __expf(-sv));
    }
    int i0 = 0;
    for (int e = 1; e < E; e++)
      if (gg[e] > gg[i0]) i0 = e;
    int i1 = -1;
    for (int e = 0; e < E; e++) {
      if (e == i0) continue;
      if (i1 < 0 || gg[e] > gg[i1]) i1 = e;
    }
    float mm[E];
    for (int e = 0; e < E; e++) mm[e] = 0.f;
    mm[i0] = gg[i0];
    mm[i1] = gg[i1];
    for (int e = 0; e < E; e++) gm[(size_t)token * E + e] = mm[e];
  }
}

// ---------------- fp32 tiled GEMM (input projection, K=32) ----------
#define BM 64
#define BKT 16
__global__ __launch_bounds__(256) void gemm_kernel(
    const float* __restrict__ A, const float* __restrict__ Bw,
    const float* __restrict__ bias, float* __restrict__ C, int M, int N,
    int Kd) {
  __shared__ float As[BKT][BM + 1];
  __shared__ float Bs[BKT][BM + 1];
  int bm = blockIdx.y * BM, bn = blockIdx.x * BM;
  int tid = threadIdx.x;
  int tx = tid & 15, ty = tid >> 4;
  float acc[4][4] = {};
  for (int k0 = 0; k0 < Kd; k0 += BKT) {
#pragma unroll
    for (int j = 0; j < 4; j++) {
      int i = tid + j * 256;
      int r = i >> 4, c = i & 15;
      As[c][r] = A[(size_t)(bm + r) * Kd + k0 + c];
    }
#pragma unroll
    for (int j = 0; j < 4; j++) {
      int i = tid + j * 256;
      int n = i >> 4, c = i & 15;
      Bs[c][n] = Bw[(size_t)(bn + n) * Kd + k0 + c];
    }
    __syncthreads();
#pragma unroll
    for (int kk = 0; kk < BKT; kk++) {
      float a[4], bb[4];
#pragma unroll
      for (int i2 = 0; i2 < 4; i2++) a[i2] = As[kk][ty * 4 + i2];
#pragma unroll
      for (int i2 = 0; i2 < 4; i2++) bb[i2] = Bs[kk][tx * 4 + i2];
#pragma unroll
      for (int i2 = 0; i2 < 4; i2++)
#pragma unroll
        for (int j2 = 0; j2 < 4; j2++) acc[i2][j2] += a[i2] * bb[j2];
    }
    __syncthreads();
  }
#pragma unroll
  for (int i2 = 0; i2 < 4; i2++) {
    int row = bm + ty * 4 + i2;
#pragma unroll
    for (int j2 = 0; j2 < 4; j2++) {
      int col = bn + tx * 4 + j2;
      C[(size_t)row * N + col] = acc[i2][j2] + bias[col];
    }
  }
}

// ---------------- bf16 MFMA GEMM, 64xBN, BK=32, dbuf, 1 barrier/iter -----
template <int NI>
__global__ __launch_bounds__(256) void mfma_gemm(
    const __bf16* __restrict__ A, int lda, long long aZ,
    const __bf16* __restrict__ Bt, long long bZ, const float* __restrict__ bias,
    long long biasZ, float* __restrict__ C, __bf16* __restrict__ Cbf, int ldc,
    long long cZ, const float* __restrict__ rowScale, int rsLd, int K,
    int accum, int relu, int rope) {
  constexpr int BN = NI * 32;
  __shared__ __bf16 As[2][64 * 32];
  __shared__ __bf16 Bs[2][BN * 32];
  int z = blockIdx.z;
  int bm = blockIdx.y * 64, bn = blockIdx.x * BN;
  int tid = threadIdx.x, lane = tid & 63, wv = tid >> 6;
  int wr = wv >> 1, wc = wv & 1;
  int half = lane >> 4, mrow = lane & 15;
  const __bf16* Ab = A + (size_t)z * aZ + (size_t)bm * lda;
  const __bf16* Bb = Bt + (size_t)z * bZ + (size_t)bn * K;
  fx4 acc[2][NI] = {};
  int aslot[2], bslot[NI];
#pragma unroll
  for (int i = 0; i < 2; i++) {
    int row = wr * 32 + i * 16 + mrow;
    aslot[i] = row * 4 + (half ^ ((row >> 1) & 3));
  }
#pragma unroll
  for (int j = 0; j < NI; j++) {
    int row = wc * (NI * 16) + j * 16 + mrow;
    bslot[j] = row * 4 + (half ^ ((row >> 1) & 3));
  }
  // staging address precompute (A: 256 chunks; B: NI/2 * 256 chunks)
  int rowa = tid >> 2, kca = (((tid & 3) ^ ((rowa >> 1) & 3)) << 3);

  auto stage = [&](int buf, int k0) {
    __builtin_amdgcn_global_load_lds(
        (const __attribute__((address_space(1))) void*)(Ab +
                                                        (size_t)rowa * lda +
                                                        k0 + kca),
        (__attribute__((address_space(3))) void*)(&As[buf][tid * 8]), 16, 0, 0);
#pragma unroll
    for (int it = 0; it < NI / 2; it++) {
      int c = tid + it * 256;
      int row = c >> 2;
      int kc = (((c & 3) ^ ((row >> 1) & 3)) << 3);
      __builtin_amdgcn_global_load_lds(
          (const __attribute__((address_space(1))) void*)(Bb + (size_t)row * K +
                                                          k0 + kc),
          (__attribute__((address_space(3))) void*)(&Bs[buf][c * 8]), 16, 0, 0);
    }
  };
  stage(0, 0);
  for (int k0 = 0; k0 < K; k0 += 32) {
    int cur = (k0 >> 5) & 1;
    __syncthreads();  // drains vmcnt: buffer `cur` ready; prior reads done
    if (k0 + 32 < K) stage(cur ^ 1, k0 + 32);
    bf16x8 af[2], bfr[NI];
#pragma unroll
    for (int i = 0; i < 2; i++)
      af[i] = *(const bf16x8*)(&As[cur][aslot[i] * 8]);
#pragma unroll
    for (int j = 0; j < NI; j++)
      bfr[j] = *(const bf16x8*)(&Bs[cur][bslot[j] * 8]);
#pragma unroll
    for (int i = 0; i < 2; i++)
#pragma unroll
      for (int j = 0; j < NI; j++)
        acc[i][j] = __builtin_amdgcn_mfma_f32_16x16x32_bf16(af[i], bfr[j],
                                                            acc[i][j], 0, 0, 0);
  }
  int doRope = rope && (z < 2);
#pragma unroll
  for (int i = 0; i < 2; i++) {
#pragma unroll
    for (int r = 0; r < 4; r++) {
      int row = bm + wr * 32 + i * 16 + half * 4 + r;
      float rs = rowScale ? rowScale[(size_t)row * rsLd + z] : 1.f;
      float vv[NI];
#pragma unroll
      for (int j = 0; j < NI; j++) {
        int col = bn + wc * (NI * 16) + j * 16 + mrow;
        float val = acc[i][j][r];
        if (bias) val += bias[(size_t)z * biasZ + col];
        if (relu) val = fmaxf(val, 0.f);
        vv[j] = val * rs;
      }
      if (doRope && NI == 4) {
        int spos = row & (S - 1);
#pragma unroll
        for (int jj = 0; jj < 2; jj++) {
          int hd = jj * 16 + mrow;  // 0..31
          float invf = exp2f(hd * -0.4152410118609825f);
          float ang = (float)spos * invf;
          float sn, cs;
          __sincosf(ang, &sn, &cs);
          float a0 = vv[jj], a1 = vv[jj + 2];
          vv[jj] = a0 * cs - a1 * sn;
          vv[jj + 2] = a1 * cs + a0 * sn;
        }
      }
#pragma unroll
      for (int j = 0; j < NI; j++) {
        int col = bn + wc * (NI * 16) + j * 16 + mrow;
        size_t addr = (size_t)z * cZ + (size_t)row * ldc + col;
        if (Cbf)
          Cbf[addr] = (__bf16)vv[j];
        else if (accum)
          C[addr] += vv[j];
        else
          C[addr] = vv[j];
      }
    }
  }
}

// ---------------- fp32 -> bf16 transpose+convert (z-split strides) --------
__global__ void transpose_cvt(const float* __restrict__ src, long long srcZ,
                              __bf16* __restrict__ dst, int zmod,
                              long long dstZa, long long dstZb, int R, int C,
                              int dstLd) {
  __shared__ float t[32][33];
  int r0 = blockIdx.y * 32, c0 = blockIdx.x * 32;
  int z = blockIdx.z;
  src += (size_t)z * srcZ;
  dst += (size_t)(z / zmod) * dstZb + (size_t)(z % zmod) * dstZa;
  int tx = threadIdx.x, ty = threadIdx.y;
#pragma unroll
  for (int i = 0; i < 4; i++) {
    int r = r0 + ty + i * 8;
    t[ty + i * 8][tx] = src[(size_t)r * C + c0 + tx];
  }
  __syncthreads();
#pragma unroll
  for (int i = 0; i < 4; i++) {
    int c = c0 + ty + i * 8;
    dst[(size_t)c * dstLd + r0 + tx] = (__bf16)t[tx][ty + i * 8];
  }
}

__global__ void cvt_kernel(const float* __restrict__ s, __bf16* __restrict__ d,
                           int n) {
  for (int i = blockIdx.x * 256 + threadIdx.x; i < n; i += gridDim.x * 256)
    d[i] = (__bf16)s[i];
}

// ---------------- concat biases for all layers ---------------------------
__global__ void bias_all(const float* __restrict__ a,
                         const float* __restrict__ b,
                         const float* __restrict__ c, float* __restrict__ dst) {
  int i = blockIdx.x * 256 + threadIdx.x;
  if (i >= LNUM * 3 * D) return;
  int l = i / (3 * D), r = i % (3 * D);
  int w = r / D, d = r % D;
  const float* src = w == 0 ? a : (w == 1 ? b : c);
  dst[i] = src[l * D + d];
}

// ---------------- barrier-free split-S flash attention -------------------
// Block: 32 Q-rows, 4 waves. Wave w owns keys [w*256, w*256+256), 8 tiles of
// 32, wave-private LDS (Vt transposed + Pb staging), K-frags from global.
// End: merge partial (m, l, O) across waves via LDS.
#define VT2 34  // Vt row stride (bf16): [d=64][t=32]+2 pad -> 2-way banks
#define PB2 68  // Pb row stride (bf16): [m=32][k=32]+4 pad -> 2-way banks
#define AWB (64 * VT2 * 2 + 32 * PB2 * 2)  // 4352 + 4352 = 8704 B per wave
__global__ __launch_bounds__(256) void attn_split(
    const __bf16* __restrict__ qb, const __bf16* __restrict__ kb,
    const __bf16* __restrict__ vb, __bf16* __restrict__ obf) {
  __shared__ char sh[4 * AWB];  // 34816 B; overlaid by combine buffers
  int q0 = blockIdx.x * 32, hh = blockIdx.y, b = blockIdx.z;
  int tid = threadIdx.x, lane = tid & 63, wv = tid >> 6;
  int col = lane & 15, half = lane >> 4;
  const size_t headoff = (size_t)hh * HD;
  const float scale = 0.125f;  // HD^-0.5
  __bf16* Vt = (__bf16*)(sh + wv * AWB);
  __bf16* Pb = Vt + 64 * VT2;

  bf16x8 qf[2][2];
#pragma unroll
  for (int mi = 0; mi < 2; mi++) {
    const __bf16* qp = qb + (size_t)(b * S + q0 + mi * 16 + col) * D + headoff;
    qf[mi][0] = *(const bf16x8*)(qp + half * 8);
    qf[mi][1] = *(const bf16x8*)(qp + 32 + half * 8);
  }
  fx4 Oacc[2][4] = {};
  float m_i[2][4], l_i[2][4];
#pragma unroll
  for (int mi = 0; mi < 2; mi++)
#pragma unroll
    for (int r = 0; r < 4; r++) {
      m_i[mi][r] = -1e30f;
      l_i[mi][r] = 0.f;
    }
  const __bf16* kbh = kb + (size_t)(b * S) * D + headoff;
  const __bf16* vbh = vb + (size_t)(b * S) * D + headoff;
  int dg = lane & 7, tp = lane >> 3;

  for (int t0 = wv * 256; t0 < wv * 256 + 256; t0 += 32) {
    // V tile -> Vt[d][t] (packed b32 pair writes, conflict-free stride)
#pragma unroll
    for (int s2 = 0; s2 < 2; s2++) {
      int t = s2 * 16 + tp * 2;
      bf16x8 v0 = *(const bf16x8*)(vbh + (size_t)(t0 + t) * D + dg * 8);
      bf16x8 v1 = *(const bf16x8*)(vbh + (size_t)(t0 + t + 1) * D + dg * 8);
#pragma unroll
      for (int j = 0; j < 8; j++) {
        union {
          __bf16 h[2];
          unsigned int u;
        } pk;
        pk.h[0] = v0[j];
        pk.h[1] = v1[j];
        *(unsigned int*)(Vt + (dg * 8 + j) * VT2 + t) = pk.u;
      }
    }
    // S = Q @ K^T : K-fragments directly from global (contiguous per lane)
    fx4 sacc[2][2] = {};
#pragma unroll
    for (int n = 0; n < 2; n++) {
      const __bf16* kp = kbh + (size_t)(t0 + n * 16 + col) * D;
      bf16x8 b0 = *(const bf16x8*)(kp + half * 8);
      bf16x8 b1 = *(const bf16x8*)(kp + 32 + half * 8);
#pragma unroll
      for (int mi = 0; mi < 2; mi++) {
        sacc[mi][n] = __builtin_amdgcn_mfma_f32_16x16x32_bf16(qf[mi][0], b0,
                                                              sacc[mi][n], 0,
                                                              0, 0);
        sacc[mi][n] = __builtin_amdgcn_mfma_f32_16x16x32_bf16(qf[mi][1], b1,
                                                              sacc[mi][n], 0,
                                                              0, 0);
      }
    }
    // online softmax (wave-local, no barriers)
#pragma unroll
    for (int mi = 0; mi < 2; mi++)
#pragma unroll
      for (int r = 0; r < 4; r++) {
        float mx = fmaxf(sacc[mi][0][r], sacc[mi][1][r]);
#pragma unroll
        for (int msk = 1; msk < 16; msk <<= 1)
          mx = fmaxf(mx, __shfl_xor(mx, msk));
        float nm = fmaxf(m_i[mi][r], mx * scale);
        float alpha = __expf(m_i[mi][r] - nm);
        m_i[mi][r] = nm;
        l_i[mi][r] *= alpha;
#pragma unroll
        for (int n = 0; n < 4; n++) Oacc[mi][n][r] *= alpha;
        float part = 0.f;
        int prow = (mi * 16 + half * 4 + r) * PB2;
#pragma unroll
        for (int n = 0; n < 2; n++) {
          float p = __expf(sacc[mi][n][r] * scale - nm);
          part += p;
          Pb[prow + n * 16 + col] = (__bf16)p;
        }
#pragma unroll
        for (int msk = 1; msk < 16; msk <<= 1) part += __shfl_xor(part, msk);
        l_i[mi][r] += part;
      }
    // O += P @ V  (single K=32 chunk)
#pragma unroll
    for (int mi = 0; mi < 2; mi++) {
      bf16x8 af = *(const bf16x8*)(Pb + (mi * 16 + col) * PB2 + half * 8);
#pragma unroll
      for (int n = 0; n < 4; n++) {
        bf16x8 bv = *(const bf16x8*)(Vt + (n * 16 + col) * VT2 + half * 8);
        Oacc[mi][n] = __builtin_amdgcn_mfma_f32_16x16x32_bf16(af, bv,
                                                              Oacc[mi][n], 0,
                                                              0, 0);
      }
    }
  }
  // ---- merge the 4 waves' partial results ----
  __syncthreads();
  float* Mw = (float*)sh;  // [4][32]
  float* Lw = Mw + 128;    // [4][32]
  float* Ow = Lw + 128;    // [4][32][65]
#pragma unroll
  for (int mi = 0; mi < 2; mi++)
#pragma unroll
    for (int r = 0; r < 4; r++) {
      int row = mi * 16 + half * 4 + r;
      if (col == 0) {
        Mw[wv * 32 + row] = m_i[mi][r];
        Lw[wv * 32 + row] = l_i[mi][r];
      }
#pragma unroll
      for (int n = 0; n < 4; n++)
        Ow[wv * 2080 + row * 65 + n * 16 + col] = Oacc[mi][n][r];
    }
  __syncthreads();
#pragma unroll
  for (int kk = 0; kk < 8; kk++) {
    int idx = tid + kk * 256;
    int row = idx >> 6, c = idx & 63;
    float M = Mw[row];
#pragma unroll
    for (int w = 1; w < 4; w++) M = fmaxf(M, Mw[w * 32 + row]);
    float o = 0.f, l = 0.f;
#pragma unroll
    for (int w = 0; w < 4; w++) {
      float a = __expf(Mw[w * 32 + row] - M);
      o += a * Ow[w * 2080 + row * 65 + c];
      l += a * Lw[w * 32 + row];
    }
    obf[(size_t)(b * S + q0 + row) * D + headoff + c] = (__bf16)(o / l);
  }
}

// ---------------- final head: last token only ----------------
__global__ __launch_bounds__(256) void final_kernel(
    const float* __restrict__ h, const float* __restrict__ tg,
    const float* __restrict__ tb, const float* __restrict__ dg,
    const float* __restrict__ db, const float* __restrict__ ow,
    const float* __restrict__ ob, float* __restrict__ out) {
  int b = blockIdx.x;
  int tid = threadIdx.x;
  __shared__ float scratch[4];
  __shared__ float yf[D];
  const float* p = h + ((size_t)(b * S + (S - 1))) * D;
  float x[4];
  float s = 0.f, sq = 0.f;
#pragma unroll
  for (int i = 0; i < 4; i++) {
    x[i] = p[tid + i * 256];
    s += x[i];
    sq += x[i] * x[i];
  }
  s = block_reduce_sum256(s, scratch);
  sq = block_reduce_sum256(sq, scratch);
  float mean = s * (1.f / D);
  float inv = rsqrtf(sq * (1.f / D) - mean * mean + EPS);
  float y[4];
  s = 0.f;
  sq = 0.f;
#pragma unroll
  for (int i = 0; i < 4; i++) {
    int d = tid + i * 256;
    y[i] = (x[i] - mean) * inv * tg[d] + tb[d];
    s += y[i];
    sq += y[i] * y[i];
  }
  s = block_reduce_sum256(s, scratch);
  sq = block_reduce_sum256(sq, scratch);
  float mean2 = s * (1.f / D);
  float inv2 = rsqrtf(sq * (1.f / D) - mean2 * mean2 + EPS);
#pragma unroll
  for (int i = 0; i < 4; i++) {
    int d = tid + i * 256;
    yf[d] = (y[i] - mean2) * inv2 * dg[d] + db[d];
  }
  __syncthreads();
  for (int oo = 0; oo < NOUT; oo++) {
    float part = 0.f;
    for (int d = tid; d < D; d += 256) part += yf[d] * ow[(size_t)oo * D + d];
    part = block_reduce_sum256(part, scratch);
    if (tid == 0) out[b * NOUT + oo] = part + ob[oo];
  }
}

extern "C" void kernel_launch(void* const* d_in, const int* in_sizes, int n_in,
                              void* d_out, int out_size, void* d_ws,
                              size_t ws_size, hipStream_t stream) {
  const float* x = (const float*)d_in[0];
  const float* ln1_g = (const float*)d_in[1];
  const float* ln1_b = (const float*)d_in[2];
  const float* qw = (const float*)d_in[3];
  const float* qb_ = (const float*)d_in[4];
  const float* kw = (const float*)d_in[5];
  const float* kb_ = (const float*)d_in[6];
  const float* vw = (const float*)d_in[7];
  const float* vb_ = (const float*)d_in[8];
  const float* ow = (const float*)d_in[9];
  const float* ob = (const float*)d_in[10];
  const float* ln2_g = (const float*)d_in[11];
  const float* ln2_b = (const float*)d_in[12];
  const float* selw = (const float*)d_in[13];
  const float* w1 = (const float*)d_in[14];
  const float* w2 = (const float*)d_in[15];
  const float* lntg = (const float*)d_in[16];
  const float* lntb = (const float*)d_in[17];
  const float* lndg = (const float*)d_in[18];
  const float* lndb = (const float*)d_in[19];
  const float* inw = (const float*)d_in[20];
  const float* inb = (const float*)d_in[21];
  const float* outw = (const float*)d_in[22];
  const float* outb = (const float*)d_in[23];
  float* out = (float*)d_out;

  // ---- workspace layout (~64 MB) ----
  float* h = (float*)d_ws;                          // TOK*D f32
  float* gm = h + (size_t)TOK * D;                  // TOK*E
  float* qkvbias = gm + (size_t)TOK * E;            // L*3*D
  __bf16* xnb = (__bf16*)(qkvbias + LNUM * 3 * D);  // TOK*D
  __bf16* qkvbf = xnb + (size_t)TOK * D;            // 3*TOK*D
  __bf16* obf = qkvbf + (size_t)3 * TOK * D;        // TOK*D
  __bf16* qkvt = obf + (size_t)TOK * D;             // L*3*D*D
  __bf16* owt = qkvt + (size_t)LNUM * 3 * D * D;    // L*D*D
  __bf16* w1t = owt + (size_t)LNUM * D * D;         // L*E*EH*D
  __bf16* w2t = w1t + (size_t)LNUM * E * EH * D;    // L*D*E*EH
  __bf16* midb = qkvbf;  // alias: qkv dead before MoE, rebuilt next layer

  __bf16* qbf = qkvbf;
  __bf16* kbf = qkvbf + (size_t)TOK * D;
  __bf16* vbf = qkvbf + (size_t)2 * TOK * D;

  // ---- weight prep, all layers, 7 launches ----
  transpose_cvt<<<dim3(32, 32, LNUM), dim3(32, 8), 0, stream>>>(
      qw, (long long)D * D, qkvt, 1024, (long long)3 * D * D, 0, D, D, D);
  transpose_cvt<<<dim3(32, 32, LNUM), dim3(32, 8), 0, stream>>>(
      kw, (long long)D * D, qkvt + (size_t)D * D, 1024, (long long)3 * D * D, 0,
      D, D, D);
  transpose_cvt<<<dim3(32, 32, LNUM), dim3(32, 8), 0, stream>>>(
      vw, (long long)D * D, qkvt + (size_t)2 * D * D, 1024,
      (long long)3 * D * D, 0, D, D, D);
  cvt_kernel<<<1024, 256, 0, stream>>>(ow, owt, LNUM * D * D);
  transpose_cvt<<<dim3(EH / 32, D / 32, LNUM * E), dim3(32, 8), 0, stream>>>(
      w1, (long long)D * EH, w1t, 1024, (long long)EH * D, 0, D, EH, D);
  transpose_cvt<<<dim3(D / 32, EH / 32, LNUM * E), dim3(32, 8), 0, stream>>>(
      w2, (long long)EH * D, w2t, E, EH, (long long)D * E * EH, EH, D, E * EH);
  bias_all<<<(LNUM * 3 * D + 255) / 256, 256, 0, stream>>>(qb_, kb_, vb_,
                                                           qkvbias);

  gemm_kernel<<<dim3(D / 64, TOK / 64), 256, 0, stream>>>(x, inw, inb, h, TOK,
                                                          D, DIN);
  for (int l = 0; l < LNUM; l++) {
    ln_bf_kernel<<<TOK, 256, 0, stream>>>(h, ln1_g + l * D, ln1_b + l * D, xnb);
    // q,k,v = rope(xn @ W + b) -> bf16 (z=0..2), 64x128 tile
    mfma_gemm<4><<<dim3(D / 128, TOK / 64, 3), 256, 0, stream>>>(
        xnb, D, 0, qkvt + (size_t)l * 3 * D * D, (long long)D * D,
        qkvbias + l * 3 * D, D, nullptr, qkvbf, D, (long long)TOK * D, nullptr,
        0, D, 0, 0, 1);
    attn_split<<<dim3(S / 32, H, B), 256, 0, stream>>>(qbf, kbf, vbf, obf);
    // h += o @ ow^T + ob
    mfma_gemm<2><<<dim3(D / 64, TOK / 64, 1), 256, 0, stream>>>(
        obf, D, 0, owt + (size_t)l * D * D, 0, ob + l * D, 0, h, nullptr, D, 0,
        nullptr, 0, D, 1, 0, 0);
    ln_gate_kernel<<<TOK, 256, 0, stream>>>(h, ln2_g + l * D, ln2_b + l * D,
                                            selw + (size_t)l * D * E, xnb, gm);
    // mid = relu(xn @ w1[e]) * gate  (z=8)
    mfma_gemm<2><<<dim3(EH / 64, TOK / 64, E), 256, 0, stream>>>(
        xnb, D, 0, w1t + (size_t)l * E * EH * D, (long long)EH * D, nullptr, 0,
        nullptr, midb, E * EH, EH, gm, E, D, 0, 1, 0);
    // h += mid @ w2stacked (K = 2048)
    mfma_gemm<2><<<dim3(D / 64, TOK / 64, 1), 256, 0, stream>>>(
        midb, E * EH, 0, w2t + (size_t)l * D * E * EH, 0, nullptr, 0, h,
        nullptr, D, 0, nullptr, 0, E * EH, 1, 0, 0);
  }
  final_kernel<<<B, 256, 0, stream>>>(h, lntg, lntb, lndg, lndb, outw, outb,
                                      out);
}